// Round 1
// baseline (85.990 us; speedup 1.0000x reference)
//
#include <hip/hip_runtime.h>
#include <cstdint>

typedef __attribute__((ext_vector_type(8))) short bf16x8;
typedef __attribute__((ext_vector_type(4))) float f32x4;

#if __has_builtin(__builtin_amdgcn_exp2f)
#define EXP2F(x) __builtin_amdgcn_exp2f(x)
#else
#define EXP2F(x) exp2f(x)
#endif
#if __has_builtin(__builtin_amdgcn_rcpf)
#define RCPF(x) __builtin_amdgcn_rcpf(x)
#else
#define RCPF(x) (1.0f/(x))
#endif

#define C2LOG2E 2.885390081777927f   // 2*log2(e)
#define LOG2E   1.4426950408889634f

// LDS layout (bytes)
#define OXB 0        // 65536: X_b bf16 [512][64], 16B-chunk XOR-swizzled
#define OWF 65536    // 8192: W fragment tile  (reused as agg partials later)
#define OSC 73728    // 2048: scores -> p (512 f32)
#define OXI 75776    // 256:  x_i f32
#define OAG 76032    // 256:  agg f32
#define ORD 76288    // 32:   reduction scratch (8 f32)
#define LDS_TOTAL 76352

__device__ __forceinline__ unsigned short f2bf(float f) {
    union { float f; unsigned int u; } v; v.f = f;
    return (unsigned short)((v.u + 0x7FFFu + ((v.u >> 16) & 1u)) >> 16);
}
__device__ __forceinline__ float bf2f(unsigned short h) {
    union { unsigned int u; float f; } v; v.u = ((unsigned int)h) << 16; return v.f;
}

// ---------------- prep: X fp32->bf16 ; W_ap transpose ----------------
__global__ void prep_kernel(const float* __restrict__ x, const float* __restrict__ W_ap,
                            unsigned short* __restrict__ Xb, float* __restrict__ Wt) {
    int t = blockIdx.x * 256 + threadIdx.x;   // 32768 threads, 8 elems each
    const float* src = x + (size_t)t * 8;
    float4 a = *(const float4*)(src);
    float4 b = *(const float4*)(src + 4);
    unsigned int p0 = (unsigned int)f2bf(a.x) | ((unsigned int)f2bf(a.y) << 16);
    unsigned int p1 = (unsigned int)f2bf(a.z) | ((unsigned int)f2bf(a.w) << 16);
    unsigned int p2 = (unsigned int)f2bf(b.x) | ((unsigned int)f2bf(b.y) << 16);
    unsigned int p3 = (unsigned int)f2bf(b.z) | ((unsigned int)f2bf(b.w) << 16);
    *(int4*)(Xb + (size_t)t * 8) = make_int4((int)p0, (int)p1, (int)p2, (int)p3);
    if (t < 64 * 64) Wt[t] = W_ap[(t & 63) * 64 + (t >> 6)];  // Wt[o][d] = W_ap[d][o]
}

// ---------------- main: one block per (b,i) ----------------
__global__ __launch_bounds__(256, 2) void gat_kernel(
    const float* __restrict__ x, const float* __restrict__ b_ap, const float* __restrict__ att_w,
    const float* __restrict__ W_pa, const float* __restrict__ b_pa,
    const float* __restrict__ W_po, const float* __restrict__ b_po,
    const float* __restrict__ gma, const float* __restrict__ bta,
    const float* __restrict__ rmean, const float* __restrict__ rvar,
    const unsigned short* __restrict__ Xb, const float* __restrict__ Wt,
    float* __restrict__ out)
{
    extern __shared__ char lds[];
    float* sSc = (float*)(lds + OSC);
    float* sXi = (float*)(lds + OXI);
    float* sAg = (float*)(lds + OAG);
    float* sRd = (float*)(lds + ORD);

    const int t = threadIdx.x;
    const int l = t & 63;
    const int w = t >> 6;
    const int bid = blockIdx.x;
    const int b = bid >> 9;

    // ---- stage X_b (bf16, swizzled) + x_i (fp32) ----
    {
        const unsigned short* Xg = Xb + (size_t)b * (512 * 64);
        #pragma unroll
        for (int it = 0; it < 16; ++it) {
            int c = t + it * 256;              // chunk: j = c>>3, ch = c&7
            int j = c >> 3, ch = c & 7;
            int4 v = *(const int4*)(Xg + c * 8);
            int off = (j * 128 + ch * 16) ^ ((j & 7) << 4);
            *(int4*)(lds + OXB + off) = v;
        }
        if (t < 64) sXi[t] = x[((size_t)bid << 6) + t];
    }
    __syncthreads();

    // ---- build W_i = diag(x_i)*W_ap directly in A-fragment order ----
    // frag f = of*2+ks ; lane lc : o = of*16+(lc&15), k = ks*32+(lc>>4)*8+[0..7]
    #pragma unroll
    for (int itc = 0; itc < 2; ++itc) {
        int c  = t + itc * 256;               // 0..511
        int lc = c & 63, f = c >> 6;
        int of = f >> 1, ks = f & 1;
        int o  = of * 16 + (lc & 15);
        int k0 = ks * 32 + ((lc >> 4) << 3);
        float4 w0 = *(const float4*)(Wt + o * 64 + k0);
        float4 w1 = *(const float4*)(Wt + o * 64 + k0 + 4);
        float4 x0 = *(const float4*)(sXi + k0);
        float4 x1 = *(const float4*)(sXi + k0 + 4);
        unsigned int p0 = (unsigned int)f2bf(w0.x * x0.x) | ((unsigned int)f2bf(w0.y * x0.y) << 16);
        unsigned int p1 = (unsigned int)f2bf(w0.z * x0.z) | ((unsigned int)f2bf(w0.w * x0.w) << 16);
        unsigned int p2 = (unsigned int)f2bf(w1.x * x1.x) | ((unsigned int)f2bf(w1.y * x1.y) << 16);
        unsigned int p3 = (unsigned int)f2bf(w1.z * x1.z) | ((unsigned int)f2bf(w1.w * x1.w) << 16);
        *(int4*)(lds + OWF + c * 16) = make_int4((int)p0, (int)p1, (int)p2, (int)p3);
    }
    __syncthreads();

    // ---- A fragments (W_i^T as MFMA-A, M=o) ----
    bf16x8 af[8];
    #pragma unroll
    for (int f = 0; f < 8; ++f)
        af[f] = *(const bf16x8*)(lds + OWF + (f * 64 + l) * 16);

    // per-lane o-constants (o = of*16 + (l>>4)*4 + r)
    float n2a[16], cb[16];
    float asum = 0.f;
    #pragma unroll
    for (int of = 0; of < 4; ++of) {
        #pragma unroll
        for (int r = 0; r < 4; ++r) {
            int o = of * 16 + ((l >> 4) << 2) + r;
            float a = att_w[o];
            n2a[of * 4 + r] = -2.f * a;
            cb[of * 4 + r]  = C2LOG2E * b_ap[o];
            asum += a;
        }
    }

    // ---- GEMM: S^T[o][j] = sum_k W_i[k][o] * X[j][k] ; then scores ----
    const int wbase = w << 7;   // 128 j's per wave
    #pragma unroll
    for (int jh = 0; jh < 2; ++jh) {
        f32x4 acc[4][4];
        #pragma unroll
        for (int of = 0; of < 4; ++of)
            #pragma unroll
            for (int q = 0; q < 4; ++q)
                acc[of][q] = (f32x4){0.f, 0.f, 0.f, 0.f};

        #pragma unroll
        for (int ks = 0; ks < 2; ++ks) {
            #pragma unroll
            for (int q = 0; q < 4; ++q) {
                int j = wbase + jh * 64 + q * 16 + (l & 15);
                int off = (j * 128 + ks * 64 + ((l >> 4) << 4)) ^ ((j & 7) << 4);
                bf16x8 bx = *(const bf16x8*)(lds + OXB + off);
                #pragma unroll
                for (int of = 0; of < 4; ++of)
                    acc[of][q] = __builtin_amdgcn_mfma_f32_16x16x32_bf16(
                        af[of * 2 + ks], bx, acc[of][q], 0, 0, 0);
            }
        }
        // score_j = sum_o a_o * tanh(S + b_o) = asum - sum_o 2 a_o / (exp2(c(S+b))+1)
        #pragma unroll
        for (int q = 0; q < 4; ++q) {
            float part = asum;
            #pragma unroll
            for (int of = 0; of < 4; ++of) {
                #pragma unroll
                for (int r = 0; r < 4; ++r) {
                    float e = EXP2F(fmaf(acc[of][q][r], C2LOG2E, cb[of * 4 + r]));
                    part = fmaf(n2a[of * 4 + r], RCPF(1.f + e), part);
                }
            }
            part += __shfl_xor(part, 16);
            part += __shfl_xor(part, 32);
            if (l < 16) sSc[wbase + jh * 64 + q * 16 + l] = part;
        }
    }
    __syncthreads();

    // ---- softmax over j (512) ----
    float s0 = sSc[t], s1 = sSc[t + 256];
    float m = fmaxf(s0, s1);
    #pragma unroll
    for (int o2 = 32; o2; o2 >>= 1) m = fmaxf(m, __shfl_xor(m, o2));
    if (l == 0) sRd[w] = m;
    __syncthreads();
    m = fmaxf(fmaxf(sRd[0], sRd[1]), fmaxf(sRd[2], sRd[3]));
    float p0 = EXP2F((s0 - m) * LOG2E);
    float p1 = EXP2F((s1 - m) * LOG2E);
    sSc[t] = p0; sSc[t + 256] = p1;
    float sm = p0 + p1;
    #pragma unroll
    for (int o2 = 32; o2; o2 >>= 1) sm += __shfl_xor(sm, o2);
    if (l == 0) sRd[4 + w] = sm;
    __syncthreads();
    float inv = RCPF(sRd[4] + sRd[5] + sRd[6] + sRd[7]);

    // ---- agg[d] = inv * sum_j p_j * x[b,j,d] ----
    {
        int chk = t & 7, g = t >> 3;       // 8 d-chunks x 32 j-groups
        float a8[8];
        #pragma unroll
        for (int e = 0; e < 8; ++e) a8[e] = 0.f;
        #pragma unroll
        for (int jj = 0; jj < 16; ++jj) {
            int j = g * 16 + jj;
            float pj = sSc[j];
            int off = (j * 128 + chk * 16) ^ ((j & 7) << 4);
            bf16x8 v = *(const bf16x8*)(lds + OXB + off);
            #pragma unroll
            for (int e = 0; e < 8; ++e)
                a8[e] = fmaf(bf2f((unsigned short)v[e]), pj, a8[e]);
        }
        float* sAP = (float*)(lds + OWF);   // reuse W-frag space
        #pragma unroll
        for (int e = 0; e < 8; ++e) sAP[g * 64 + chk * 8 + e] = a8[e];
        __syncthreads();
        if (t < 64) {
            float s = 0.f;
            #pragma unroll
            for (int g2 = 0; g2 < 32; ++g2) s += sAP[g2 * 64 + t];
            sAg[t] = s * inv;
        }
    }
    __syncthreads();

    // ---- h = agg@W_pa + b_pa + x_i@W_po + b_po ; BN ; SELU ----
    if (t < 64) {
        int o = t;
        float hv = b_pa[o] + b_po[o];
        #pragma unroll 8
        for (int d = 0; d < 64; ++d) {
            hv = fmaf(sAg[d], W_pa[d * 64 + o], hv);
            hv = fmaf(sXi[d], W_po[d * 64 + o], hv);
        }
        float istd = rsqrtf(rvar[o] + 1e-5f);
        hv = (hv - rmean[o]) * istd * gma[o] + bta[o];
        const float alpha = 1.6732632423543772f, scale = 1.0507009873554805f;
        float neg = alpha * (EXP2F(hv * LOG2E) - 1.0f);
        out[((size_t)bid << 6) + o] = scale * (hv > 0.f ? hv : neg);
    }
}

extern "C" void kernel_launch(void* const* d_in, const int* in_sizes, int n_in,
                              void* d_out, int out_size, void* d_ws, size_t ws_size,
                              hipStream_t stream) {
    const float* x     = (const float*)d_in[0];
    const float* W_ap  = (const float*)d_in[1];
    const float* b_ap  = (const float*)d_in[2];
    const float* att_w = (const float*)d_in[3];
    const float* W_pa  = (const float*)d_in[4];
    const float* b_pa  = (const float*)d_in[5];
    const float* W_po  = (const float*)d_in[6];
    const float* b_po  = (const float*)d_in[7];
    const float* gma   = (const float*)d_in[8];
    const float* bta   = (const float*)d_in[9];
    const float* rmean = (const float*)d_in[10];
    const float* rvar  = (const float*)d_in[11];

    unsigned short* Xb = (unsigned short*)d_ws;              // 512 KB bf16 X
    float* Wt          = (float*)((char*)d_ws + 512 * 1024); // 16 KB W_ap^T
    float* out         = (float*)d_out;

    prep_kernel<<<128, 256, 0, stream>>>(x, W_ap, Xb, Wt);
    (void)hipFuncSetAttribute((const void*)gat_kernel,
                              hipFuncAttributeMaxDynamicSharedMemorySize, LDS_TOTAL);
    gat_kernel<<<4096, 256, LDS_TOTAL, stream>>>(x, b_ap, att_w, W_pa, b_pa, W_po, b_po,
                                                 gma, bta, rmean, rvar, Xb, Wt, out);
}